// Round 6
// baseline (426.602 us; speedup 1.0000x reference)
//
#include <hip/hip_runtime.h>
#include <math.h>

// Plenoxels renderer, round 6.
//  - fp16 voxel-major 64B records (one cacheline/voxel), 134MB, L3-resident.
//  - render: lane handles CONSECUTIVE sample pairs (2k,2k+1); ~half the pairs
//    share a trilerp cell -> one 8-record fetch feeds both samples (per-corner
//    SH dot computed once, fma'd into both accumulator sets). Lanes whose
//    pair crosses a cell boundary run a masked second 8-corner loop.
//  - 2 pairs/lane, 256-sample chunks, 2 chunks/ray, 8192 waves.
//  - whole-wave early exit when the chunk starts beyond the ray's box exit.

typedef _Float16 h8 __attribute__((ext_vector_type(8)));

namespace {
constexpr float kRadius   = 1.3f;
constexpr int   kRes      = 128;
constexpr float kStep     = 2.0f * 1.3f / 128.0f / 2.0f;   // 0.01015625
constexpr int   kNI       = 443;                           // N_INTRS - 1
constexpr int   kNRays    = 4096;
constexpr int   kChStride = kRes * kRes * kRes;            // 2097152 voxels
constexpr int   kCh       = 28;
constexpr int   kVoxPad   = 32;                            // halves per 64B record
constexpr size_t kVoxBytes = (size_t)kChStride * kVoxPad * sizeof(_Float16);
constexpr int   kChunks   = 2;                             // 256-sample chunks
constexpr int   kChunks7  = 7;                             // fallback: 64-sample
}

// ---------------------------------------------------------------------------
// Convert grid[c][v] (f32 channel-major) -> vox[v] = 32 halves (64B record).
// ---------------------------------------------------------------------------
__global__ __launch_bounds__(256)
void convert_grid(const float* __restrict__ grid, _Float16* __restrict__ vox)
{
    const int v = blockIdx.x * 256 + threadIdx.x;          // 8192 blocks
    h8 o[4];
    #pragma unroll
    for (int c = 0; c < kCh; ++c)
        o[c >> 3][c & 7] = (_Float16)__builtin_nontemporal_load(grid + (size_t)c * kChStride + v);
    o[3][4] = o[3][5] = o[3][6] = o[3][7] = (_Float16)0.f;

    h8* dst = (h8*)(vox + (size_t)v * kVoxPad);
    dst[0] = o[0]; dst[1] = o[1]; dst[2] = o[2]; dst[3] = o[3];
}

// ---------------------------------------------------------------------------
struct Sample {
    float alpha;   // 1 - exp(-sigma*dist)
    float a;       // 1 - alpha + 1e-10
    float rp0, rp1, rp2;
    bool  inb;
};

// Load one 64B record, compute SH dots (r,g,b) + sigma channel once,
// fma into two accumulator sets with weights wa (set0) and wb (set1).
__device__ __forceinline__ void corner_accum2(
    const _Float16* __restrict__ rec, const float* __restrict__ shm,
    float wa, float wb,
    float& a0, float& a1, float& a2, float& asig,
    float& b0, float& b1, float& b2, float& bsig)
{
    const h8* vp = (const h8*)rec;
    const h8 q0 = vp[0], q1 = vp[1], q2 = vp[2], q3 = vp[3];

    float f[28];
    #pragma unroll
    for (int i = 0; i < 8; ++i) f[i]      = (float)q0[i];
    #pragma unroll
    for (int i = 0; i < 8; ++i) f[8 + i]  = (float)q1[i];
    #pragma unroll
    for (int i = 0; i < 8; ++i) f[16 + i] = (float)q2[i];
    #pragma unroll
    for (int i = 0; i < 4; ++i) f[24 + i] = (float)q3[i];

    float r = 0.f, g = 0.f, b = 0.f;
    #pragma unroll
    for (int j = 0; j < 9; ++j) {
        r = fmaf(shm[j], f[j],      r);
        g = fmaf(shm[j], f[9 + j],  g);
        b = fmaf(shm[j], f[18 + j], b);
    }
    a0 = fmaf(wa, r, a0);  a1 = fmaf(wa, g, a1);
    a2 = fmaf(wa, b, a2);  asig = fmaf(wa, f[27], asig);
    b0 = fmaf(wb, r, b0);  b1 = fmaf(wb, g, b1);
    b2 = fmaf(wb, b, b2);  bsig = fmaf(wb, f[27], bsig);
}

// Single-accumulator variant (for the masked crossing loop).
__device__ __forceinline__ void corner_accum1(
    const _Float16* __restrict__ rec, const float* __restrict__ shm,
    float w, float& a0, float& a1, float& a2, float& asig)
{
    const h8* vp = (const h8*)rec;
    const h8 q0 = vp[0], q1 = vp[1], q2 = vp[2], q3 = vp[3];

    float f[28];
    #pragma unroll
    for (int i = 0; i < 8; ++i) f[i]      = (float)q0[i];
    #pragma unroll
    for (int i = 0; i < 8; ++i) f[8 + i]  = (float)q1[i];
    #pragma unroll
    for (int i = 0; i < 8; ++i) f[16 + i] = (float)q2[i];
    #pragma unroll
    for (int i = 0; i < 4; ++i) f[24 + i] = (float)q3[i];

    float r = 0.f, g = 0.f, b = 0.f;
    #pragma unroll
    for (int j = 0; j < 9; ++j) {
        r = fmaf(shm[j], f[j],      r);
        g = fmaf(shm[j], f[9 + j],  g);
        b = fmaf(shm[j], f[18 + j], b);
    }
    a0 = fmaf(w, r, a0);  a1 = fmaf(w, g, a1);
    a2 = fmaf(w, b, a2);  asig = fmaf(w, f[27], asig);
}

// ---------------------------------------------------------------------------
// Evaluate a consecutive sample pair (k0, k0+1) sharing cell fetches.
// ---------------------------------------------------------------------------
__device__ __forceinline__ void eval_pair(
    int k0, float start, float ox, float oy, float oz,
    float dx, float dy, float dz, float dist,
    const float* __restrict__ shm, const _Float16* __restrict__ vox,
    Sample& s0, Sample& s1)
{
    s0.alpha = 0.f; s0.a = 1.f; s0.rp0 = s0.rp1 = s0.rp2 = 0.f; s0.inb = false;
    s1.alpha = 0.f; s1.a = 1.f; s1.rp0 = s1.rp1 = s1.rp2 = 0.f; s1.inb = false;

    const bool v0 = (k0 < kNI), v1 = (k0 + 1 < kNI);
    const float t0 = start + (float)k0 * kStep;
    const float t1 = t0 + kStep;

    const float px0 = ox + t0*dx, py0 = oy + t0*dy, pz0 = oz + t0*dz;
    const float px1 = ox + t1*dx, py1 = oy + t1*dy, pz1 = oz + t1*dz;

    s0.inb = v0 && (px0 > -kRadius) && (px0 < kRadius) &&
                   (py0 > -kRadius) && (py0 < kRadius) &&
                   (pz0 > -kRadius) && (pz0 < kRadius);
    s1.inb = v1 && (px1 > -kRadius) && (px1 < kRadius) &&
                   (py1 > -kRadius) && (py1 < kRadius) &&
                   (pz1 > -kRadius) && (pz1 < kRadius);

    const float cx0 = fminf(fmaxf((px0*(1.0f/kRadius) + 1.0f)*0.5f*127.0f, 0.0f), 127.0f);
    const float cy0 = fminf(fmaxf((py0*(1.0f/kRadius) + 1.0f)*0.5f*127.0f, 0.0f), 127.0f);
    const float cz0 = fminf(fmaxf((pz0*(1.0f/kRadius) + 1.0f)*0.5f*127.0f, 0.0f), 127.0f);
    const float cx1 = fminf(fmaxf((px1*(1.0f/kRadius) + 1.0f)*0.5f*127.0f, 0.0f), 127.0f);
    const float cy1 = fminf(fmaxf((py1*(1.0f/kRadius) + 1.0f)*0.5f*127.0f, 0.0f), 127.0f);
    const float cz1 = fminf(fmaxf((pz1*(1.0f/kRadius) + 1.0f)*0.5f*127.0f, 0.0f), 127.0f);

    const int ix = (int)floorf(cx0), iy = (int)floorf(cy0), iz = (int)floorf(cz0);
    const int jx = (int)floorf(cx1), jy = (int)floorf(cy1), jz = (int)floorf(cz1);

    const bool same = s0.inb && s1.inb && (ix == jx) && (iy == jy) && (iz == jz);

    float sig0 = 0.f, sig1 = 0.f;

    if (s0.inb) {
        const int ix1 = min(ix + 1, 127), iy1 = min(iy + 1, 127), iz1 = min(iz + 1, 127);
        const float fx = cx0 - (float)ix, fy = cy0 - (float)iy, fz = cz0 - (float)iz;
        const float gx = 1.f - fx, gy = 1.f - fy, gz = 1.f - fz;

        // sample1 weights relative to cell A (valid only when same cell)
        const float m  = same ? 1.f : 0.f;
        const float hx = (cx1 - (float)ix) * m;     // in [0,1) when same
        const float hy = (cy1 - (float)iy) * m;
        const float hz = (cz1 - (float)iz) * m;
        const float kx = m - hx, ky = m - hy, kz = m - hz;   // m*(1-f)

        const int o[8] = {
            iz *(kRes*kRes) + iy *kRes + ix,
            iz *(kRes*kRes) + iy *kRes + ix1,
            iz *(kRes*kRes) + iy1*kRes + ix,
            iz *(kRes*kRes) + iy1*kRes + ix1,
            iz1*(kRes*kRes) + iy *kRes + ix,
            iz1*(kRes*kRes) + iy *kRes + ix1,
            iz1*(kRes*kRes) + iy1*kRes + ix,
            iz1*(kRes*kRes) + iy1*kRes + ix1 };
        const float wa[8] = {
            gz*gy*gx, gz*gy*fx, gz*fy*gx, gz*fy*fx,
            fz*gy*gx, fz*gy*fx, fz*fy*gx, fz*fy*fx };
        const float wb[8] = {
            kz*ky*kx, kz*ky*hx, kz*hy*kx, kz*hy*hx,
            hz*ky*kx, hz*ky*hx, hz*hy*kx, hz*hy*hx };

        #pragma unroll
        for (int c = 0; c < 8; ++c)
            corner_accum2(vox + (size_t)o[c] * kVoxPad, shm, wa[c], wb[c],
                          s0.rp0, s0.rp1, s0.rp2, sig0,
                          s1.rp0, s1.rp1, s1.rp2, sig1);
    }

    if (s1.inb && !same) {
        const int jx1 = min(jx + 1, 127), jy1 = min(jy + 1, 127), jz1 = min(jz + 1, 127);
        const float fx = cx1 - (float)jx, fy = cy1 - (float)jy, fz = cz1 - (float)jz;
        const float gx = 1.f - fx, gy = 1.f - fy, gz = 1.f - fz;

        const int o[8] = {
            jz *(kRes*kRes) + jy *kRes + jx,
            jz *(kRes*kRes) + jy *kRes + jx1,
            jz *(kRes*kRes) + jy1*kRes + jx,
            jz *(kRes*kRes) + jy1*kRes + jx1,
            jz1*(kRes*kRes) + jy *kRes + jx,
            jz1*(kRes*kRes) + jy *kRes + jx1,
            jz1*(kRes*kRes) + jy1*kRes + jx,
            jz1*(kRes*kRes) + jy1*kRes + jx1 };
        const float w[8] = {
            gz*gy*gx, gz*gy*fx, gz*fy*gx, gz*fy*fx,
            fz*gy*gx, fz*gy*fx, fz*fy*gx, fz*fy*fx };

        #pragma unroll
        for (int c = 0; c < 8; ++c)
            corner_accum1(vox + (size_t)o[c] * kVoxPad, shm, w[c],
                          s1.rp0, s1.rp1, s1.rp2, sig1);
    }

    sig0 = fmaxf(sig0, 0.0f);
    sig1 = fmaxf(sig1, 0.0f);
    if (s0.inb) { s0.alpha = 1.0f - expf(-sig0 * dist); }
    if (s1.inb) { s1.alpha = 1.0f - expf(-sig1 * dist); }
    if (k0 < kNI)     s0.a = 1.0f - s0.alpha + 1e-10f;
    if (k0 + 1 < kNI) s1.a = 1.0f - s1.alpha + 1e-10f;
}

__device__ __forceinline__ float wave_scan_prod(float a, int lane, float& total)
{
    float prod = a;
    #pragma unroll
    for (int off = 1; off < 64; off <<= 1) {
        const float y = __shfl_up(prod, off, 64);
        if (lane >= off) prod *= y;
    }
    float excl = __shfl_up(prod, 1, 64);
    if (lane == 0) excl = 1.0f;
    total = __shfl(prod, 63, 64);
    return excl;
}

// ---------------------------------------------------------------------------
// Render one 256-sample chunk of one ray per wave; lane handles consecutive
// pairs (base+2*lane, +1) and (base+128+2*lane, +1).
// ---------------------------------------------------------------------------
__global__ __launch_bounds__(256, 3)
void render_chunks(const float* __restrict__ rays_o,
                   const float* __restrict__ rays_d,
                   const _Float16* __restrict__ vox,
                   float* __restrict__ partials)           // (4096,2,5)
{
    const int lane  = threadIdx.x & 63;
    const int W     = blockIdx.x * 4 + (threadIdx.x >> 6); // 8192 waves
    const int ray   = W >> 1;
    const int chunk = W & 1;

    const float ox = rays_o[3*ray+0], oy = rays_o[3*ray+1], oz = rays_o[3*ray+2];
    const float dx = rays_d[3*ray+0], dy = rays_d[3*ray+1], dz = rays_d[3*ray+2];

    const float ppx = ( kRadius - ox)/dx, pnx = (-kRadius - ox)/dx;
    const float ppy = ( kRadius - oy)/dy, pny = (-kRadius - oy)/dy;
    const float ppz = ( kRadius - oz)/dz, pnz = (-kRadius - oz)/dz;
    const float start  = fmaxf(fminf(ppx, pnx), fmaxf(fminf(ppy, pny), fminf(ppz, pnz)));
    const float t_exit = fminf(fmaxf(ppx, pnx), fminf(fmaxf(ppy, pny), fmaxf(ppz, pnz)));

    const int base = chunk * 256;

    // whole-wave early exit: chunk starts beyond box exit (one-step margin)
    if (start + (float)base * kStep > t_exit + kStep) {
        if (lane == 0) {
            float* p = partials + (size_t)(ray * kChunks + chunk) * 5;
            p[0] = 0.f; p[1] = 0.f; p[2] = 0.f; p[3] = 0.f; p[4] = 1.f;
        }
        return;
    }

    const float dnorm = sqrtf(dx*dx + dy*dy + dz*dz);
    const float dist  = kStep * dnorm;

    float shm[9];
    shm[0] =  0.28209479177387814f;
    shm[1] = -0.4886025119029199f * dy;
    shm[2] =  0.4886025119029199f * dz;
    shm[3] = -0.4886025119029199f * dx;
    shm[4] =  1.0925484305920792f * dx * dy;
    shm[5] = -1.0925484305920792f * dy * dz;
    shm[6] =  0.31539156525252005f * (2.0f*dz*dz - dx*dx - dy*dy);
    shm[7] = -1.0925484305920792f * dx * dz;
    shm[8] =  0.5462742152960396f * (dx*dx - dy*dy);

    Sample s0, s1, s2, s3;
    eval_pair(base       + 2*lane, start, ox, oy, oz, dx, dy, dz, dist, shm, vox, s0, s1);
    eval_pair(base + 128 + 2*lane, start, ox, oy, oz, dx, dy, dz, dist, shm, vox, s2, s3);

    float P0, P1;
    const float e0 = wave_scan_prod(s0.a * s1.a, lane, P0);
    const float e1 = wave_scan_prod(s2.a * s3.a, lane, P1);

    const float w0 = s0.alpha * e0;
    const float w1 = s1.alpha * e0 * s0.a;
    const float w2 = s2.alpha * P0 * e1;
    const float w3 = s3.alpha * P0 * e1 * s2.a;

    float sR = 0.f, sG = 0.f, sB = 0.f;
    if (s0.inb) {
        sR = fmaf(w0, 1.0f / (1.0f + expf(-s0.rp0)), sR);
        sG = fmaf(w0, 1.0f / (1.0f + expf(-s0.rp1)), sG);
        sB = fmaf(w0, 1.0f / (1.0f + expf(-s0.rp2)), sB);
    }
    if (s1.inb) {
        sR = fmaf(w1, 1.0f / (1.0f + expf(-s1.rp0)), sR);
        sG = fmaf(w1, 1.0f / (1.0f + expf(-s1.rp1)), sG);
        sB = fmaf(w1, 1.0f / (1.0f + expf(-s1.rp2)), sB);
    }
    if (s2.inb) {
        sR = fmaf(w2, 1.0f / (1.0f + expf(-s2.rp0)), sR);
        sG = fmaf(w2, 1.0f / (1.0f + expf(-s2.rp1)), sG);
        sB = fmaf(w2, 1.0f / (1.0f + expf(-s2.rp2)), sB);
    }
    if (s3.inb) {
        sR = fmaf(w3, 1.0f / (1.0f + expf(-s3.rp0)), sR);
        sG = fmaf(w3, 1.0f / (1.0f + expf(-s3.rp1)), sG);
        sB = fmaf(w3, 1.0f / (1.0f + expf(-s3.rp2)), sB);
    }
    float sL = w0 + w1 + w2 + w3;
    const float P = P0 * P1;

    #pragma unroll
    for (int off = 32; off > 0; off >>= 1) {
        sR += __shfl_down(sR, off, 64);
        sG += __shfl_down(sG, off, 64);
        sB += __shfl_down(sB, off, 64);
        sL += __shfl_down(sL, off, 64);
    }

    if (lane == 0) {
        float* p = partials + (size_t)(ray * kChunks + chunk) * 5;
        p[0] = sR; p[1] = sG; p[2] = sB; p[3] = sL; p[4] = P;
    }
}

// ---------------------------------------------------------------------------
// Stitch chunk partials: acc += carry * S_c ; carry *= P_c.
// ---------------------------------------------------------------------------
__global__ __launch_bounds__(256)
void combine_chunks(const float* __restrict__ partials, float* __restrict__ out)
{
    const int r = blockIdx.x * 256 + threadIdx.x;          // 16 blocks
    const float* p = partials + (size_t)r * (kChunks * 5);

    float carry = 1.0f, aR = 0.f, aG = 0.f, aB = 0.f, aL = 0.f;
    #pragma unroll
    for (int c = 0; c < kChunks; ++c) {
        aR = fmaf(carry, p[c*5 + 0], aR);
        aG = fmaf(carry, p[c*5 + 1], aG);
        aB = fmaf(carry, p[c*5 + 2], aB);
        aL = fmaf(carry, p[c*5 + 3], aL);
        carry *= p[c*5 + 4];
    }
    const float bg = 1.0f - aL;
    out[3*r + 0] = aR + bg;
    out[3*r + 1] = aG + bg;
    out[3*r + 2] = aB + bg;
}

// ---------------------------------------------------------------------------
// Fallback: direct channel-major render (round-1 style) if ws too small.
// ---------------------------------------------------------------------------
#define TRI8(p) (w000*(p)[o000] + w001*(p)[o001] + w010*(p)[o010] + w011*(p)[o011] \
               + w100*(p)[o100] + w101*(p)[o101] + w110*(p)[o110] + w111*(p)[o111])

__global__ __launch_bounds__(256)
void plenoxel_render_direct(const float* __restrict__ rays_o,
                            const float* __restrict__ rays_d,
                            const float* __restrict__ grid,
                            float* __restrict__ out)
{
    const int lane = threadIdx.x & 63;
    const int ray  = blockIdx.x * 4 + (threadIdx.x >> 6);

    const float ox = rays_o[3*ray+0], oy = rays_o[3*ray+1], oz = rays_o[3*ray+2];
    const float dx = rays_d[3*ray+0], dy = rays_d[3*ray+1], dz = rays_d[3*ray+2];

    const float sx = fminf(( kRadius - ox)/dx, (-kRadius - ox)/dx);
    const float sy = fminf(( kRadius - oy)/dy, (-kRadius - oy)/dy);
    const float sz = fminf(( kRadius - oz)/dz, (-kRadius - oz)/dz);
    const float start = fmaxf(sx, fmaxf(sy, sz));
    const float dnorm = sqrtf(dx*dx + dy*dy + dz*dz);

    float shm[9];
    shm[0] =  0.28209479177387814f;
    shm[1] = -0.4886025119029199f * dy;
    shm[2] =  0.4886025119029199f * dz;
    shm[3] = -0.4886025119029199f * dx;
    shm[4] =  1.0925484305920792f * dx * dy;
    shm[5] = -1.0925484305920792f * dy * dz;
    shm[6] =  0.31539156525252005f * (2.0f*dz*dz - dx*dx - dy*dy);
    shm[7] = -1.0925484305920792f * dx * dz;
    shm[8] =  0.5462742152960396f * (dx*dx - dy*dy);

    float carry = 1.0f;
    float accR = 0.f, accG = 0.f, accB = 0.f, accL = 0.f;

    for (int chunk = 0; chunk < kChunks7; ++chunk) {
        const int k = chunk * 64 + lane;
        float alpha = 0.0f, a = 1.0f;
        float rp0 = 0.f, rp1 = 0.f, rp2 = 0.f;
        bool inb = false;

        if (k < kNI) {
            const float t = start + (float)k * kStep;
            const float dist = kStep * dnorm;
            const float px = ox + t*dx, py = oy + t*dy, pz = oz + t*dz;
            inb = (px > -kRadius) && (px < kRadius) &&
                  (py > -kRadius) && (py < kRadius) &&
                  (pz > -kRadius) && (pz < kRadius);
            float sigma = 0.0f;
            if (inb) {
                const float cx = fminf(fmaxf((px*(1.0f/kRadius) + 1.0f)*0.5f*127.0f, 0.0f), 127.0f);
                const float cy = fminf(fmaxf((py*(1.0f/kRadius) + 1.0f)*0.5f*127.0f, 0.0f), 127.0f);
                const float cz = fminf(fmaxf((pz*(1.0f/kRadius) + 1.0f)*0.5f*127.0f, 0.0f), 127.0f);
                const float fx0 = floorf(cx), fy0 = floorf(cy), fz0 = floorf(cz);
                const float fx = cx - fx0, fy = cy - fy0, fz = cz - fz0;
                const int ix0 = (int)fx0, iy0 = (int)fy0, iz0 = (int)fz0;
                const int ix1 = min(ix0 + 1, 127);
                const int iy1 = min(iy0 + 1, 127);
                const int iz1 = min(iz0 + 1, 127);
                const float gx0 = 1.0f - fx, gy0 = 1.0f - fy, gz0 = 1.0f - fz;
                const float w000 = gz0*gy0*gx0, w001 = gz0*gy0*fx;
                const float w010 = gz0*fy *gx0, w011 = gz0*fy *fx;
                const float w100 = fz *gy0*gx0, w101 = fz *gy0*fx;
                const float w110 = fz *fy *gx0, w111 = fz *fy *fx;
                const int o000 = iz0*(kRes*kRes) + iy0*kRes + ix0;
                const int o001 = iz0*(kRes*kRes) + iy0*kRes + ix1;
                const int o010 = iz0*(kRes*kRes) + iy1*kRes + ix0;
                const int o011 = iz0*(kRes*kRes) + iy1*kRes + ix1;
                const int o100 = iz1*(kRes*kRes) + iy0*kRes + ix0;
                const int o101 = iz1*(kRes*kRes) + iy0*kRes + ix1;
                const int o110 = iz1*(kRes*kRes) + iy1*kRes + ix0;
                const int o111 = iz1*(kRes*kRes) + iy1*kRes + ix1;
                #pragma unroll
                for (int kk = 0; kk < 9; ++kk) {
                    rp0 = fmaf(shm[kk], TRI8(grid + (kk     ) * kChStride), rp0);
                    rp1 = fmaf(shm[kk], TRI8(grid + (kk +  9) * kChStride), rp1);
                    rp2 = fmaf(shm[kk], TRI8(grid + (kk + 18) * kChStride), rp2);
                }
                sigma = fmaxf(TRI8(grid + 27 * kChStride), 0.0f);
            }
            alpha = 1.0f - expf(-sigma * dist);
            a     = 1.0f - alpha + 1e-10f;
        }

        float prod = a;
        #pragma unroll
        for (int off = 1; off < 64; off <<= 1) {
            const float y = __shfl_up(prod, off, 64);
            if (lane >= off) prod *= y;
        }
        float excl = __shfl_up(prod, 1, 64);
        if (lane == 0) excl = 1.0f;
        const float trans = carry * excl;
        const float w = alpha * trans;
        if (inb) {
            accR = fmaf(w, 1.0f / (1.0f + expf(-rp0)), accR);
            accG = fmaf(w, 1.0f / (1.0f + expf(-rp1)), accG);
            accB = fmaf(w, 1.0f / (1.0f + expf(-rp2)), accB);
        }
        accL += w;
        carry *= __shfl(prod, 63, 64);
    }

    #pragma unroll
    for (int off = 32; off > 0; off >>= 1) {
        accR += __shfl_down(accR, off, 64);
        accG += __shfl_down(accG, off, 64);
        accB += __shfl_down(accB, off, 64);
        accL += __shfl_down(accL, off, 64);
    }

    if (lane == 0) {
        const float bg = 1.0f - accL;
        out[3*ray + 0] = accR + bg;
        out[3*ray + 1] = accG + bg;
        out[3*ray + 2] = accB + bg;
    }
}

extern "C" void kernel_launch(void* const* d_in, const int* in_sizes, int n_in,
                              void* d_out, int out_size, void* d_ws, size_t ws_size,
                              hipStream_t stream) {
    const float* rays_o = (const float*)d_in[0];
    const float* rays_d = (const float*)d_in[1];
    const float* data   = (const float*)d_in[2];   // (1,28,128,128,128)
    float* out = (float*)d_out;

    const size_t partBytes = (size_t)kNRays * kChunks * 5 * sizeof(float);
    const size_t need = kVoxBytes + partBytes;     // ~134.3 MB

    if (ws_size >= need) {
        _Float16* vox = (_Float16*)d_ws;
        float* partials = (float*)((char*)d_ws + kVoxBytes);

        hipLaunchKernelGGL(convert_grid,
                           dim3(kChStride / 256), dim3(256), 0, stream,
                           data, vox);
        hipLaunchKernelGGL(render_chunks,
                           dim3(kNRays * kChunks / 4), dim3(256), 0, stream,
                           rays_o, rays_d, vox, partials);
        hipLaunchKernelGGL(combine_chunks,
                           dim3(kNRays / 256), dim3(256), 0, stream,
                           partials, out);
    } else {
        hipLaunchKernelGGL(plenoxel_render_direct,
                           dim3(kNRays / 4), dim3(256), 0, stream,
                           rays_o, rays_d, data, out);
    }
}

// Round 7
// 360.636 us; speedup vs baseline: 1.1829x; 1.1829x over previous
//
#include <hip/hip_runtime.h>
#include <math.h>

// Plenoxels renderer, round 7 = round-5 structure + 32B voxel records.
//  - record: 27 SH channels fp8(e4m3, HW cvt) + sigma fp16 + pad = 32B.
//    2 voxels/cacheline, 2x16B loads per corner (was 4).  vox = 67MB.
//  - render: 4 independent samples/lane (k,k+64,k+128,k+192), 256-sample
//    chunks, 2 chunks/ray, 8192 waves; whole-wave early exit past box exit.
//  - sigma stays fp16: it feeds the transmittance cumprod (error-sensitive);
//    fp8 noise on rgb logits is damped by sigmoid slope (<=0.25).

typedef float f2v __attribute__((ext_vector_type(2)));

namespace {
constexpr float kRadius   = 1.3f;
constexpr int   kRes      = 128;
constexpr float kStep     = 2.0f * 1.3f / 128.0f / 2.0f;   // 0.01015625
constexpr int   kNI       = 443;                           // N_INTRS - 1
constexpr int   kNRays    = 4096;
constexpr int   kChStride = kRes * kRes * kRes;            // 2097152 voxels
constexpr int   kCh       = 28;
constexpr int   kRecBytes = 32;                            // 27 fp8 + f16 sigma + pad
constexpr size_t kVoxBytes = (size_t)kChStride * kRecBytes; // 64 MiB
constexpr int   kChunks   = 2;                             // 256-sample chunks
constexpr int   kChunks7  = 7;                             // fallback: 64-sample
}

// ---------------------------------------------------------------------------
// Convert grid[c][v] (f32 channel-major) -> vox[v] 32B record.
// bytes 0..26: fp8 e4m3 ch0..26 | byte27: 0 | bytes28..29: f16 sigma | pad.
// ---------------------------------------------------------------------------
__global__ __launch_bounds__(256)
void convert_grid(const float* __restrict__ grid, unsigned char* __restrict__ vox)
{
    const int v = blockIdx.x * 256 + threadIdx.x;          // 8192 blocks
    float c[kCh];
    #pragma unroll
    for (int ch = 0; ch < kCh; ++ch)
        c[ch] = __builtin_nontemporal_load(grid + (size_t)ch * kChStride + v);

    unsigned w[8];
    #pragma unroll
    for (int i = 0; i < 6; ++i) {
        int lo = __builtin_amdgcn_cvt_pk_fp8_f32(c[4*i],   c[4*i+1], 0,  false);
        w[i]   = (unsigned)__builtin_amdgcn_cvt_pk_fp8_f32(c[4*i+2], c[4*i+3], lo, true);
    }
    {   // word 6: ch24,25,26 + pad byte
        int lo = __builtin_amdgcn_cvt_pk_fp8_f32(c[24], c[25], 0,  false);
        w[6]   = (unsigned)__builtin_amdgcn_cvt_pk_fp8_f32(c[26], 0.0f, lo, true);
    }
    {   // word 7: fp16 sigma in low half
        union { unsigned short u; _Float16 h; } cv;
        cv.h = (_Float16)c[27];
        w[7] = (unsigned)cv.u;
    }

    uint4* dst = (uint4*)(vox + (size_t)v * kRecBytes);
    dst[0] = make_uint4(w[0], w[1], w[2], w[3]);
    dst[1] = make_uint4(w[4], w[5], w[6], w[7]);
}

// ---------------------------------------------------------------------------
struct Sample {
    float alpha;   // 1 - exp(-sigma*dist)
    float a;       // 1 - alpha + 1e-10
    float rp0, rp1, rp2;
    bool  inb;
};

__device__ __forceinline__ Sample eval_sample(
    int k, float start, float ox, float oy, float oz,
    float dx, float dy, float dz, float dist,
    const float* __restrict__ shm, const unsigned char* __restrict__ vox)
{
    Sample s;
    s.alpha = 0.f; s.a = 1.f; s.rp0 = s.rp1 = s.rp2 = 0.f; s.inb = false;
    if (k >= kNI) return s;

    const float t  = start + (float)k * kStep;
    const float px = ox + t*dx;
    const float py = oy + t*dy;
    const float pz = oz + t*dz;
    s.inb = (px > -kRadius) && (px < kRadius) &&
            (py > -kRadius) && (py < kRadius) &&
            (pz > -kRadius) && (pz < kRadius);

    float sig = 0.0f;
    if (s.inb) {
        const float cx = fminf(fmaxf((px*(1.0f/kRadius) + 1.0f)*0.5f*127.0f, 0.0f), 127.0f);
        const float cy = fminf(fmaxf((py*(1.0f/kRadius) + 1.0f)*0.5f*127.0f, 0.0f), 127.0f);
        const float cz = fminf(fmaxf((pz*(1.0f/kRadius) + 1.0f)*0.5f*127.0f, 0.0f), 127.0f);
        const float fx0 = floorf(cx), fy0 = floorf(cy), fz0 = floorf(cz);
        const float fx = cx - fx0, fy = cy - fy0, fz = cz - fz0;
        const int ix0 = (int)fx0, iy0 = (int)fy0, iz0 = (int)fz0;
        const int ix1 = min(ix0 + 1, 127);
        const int iy1 = min(iy0 + 1, 127);
        const int iz1 = min(iz0 + 1, 127);

        const float gx0 = 1.0f - fx, gy0 = 1.0f - fy, gz0 = 1.0f - fz;

        const int offs[8] = {
            iz0*(kRes*kRes) + iy0*kRes + ix0,
            iz0*(kRes*kRes) + iy0*kRes + ix1,
            iz0*(kRes*kRes) + iy1*kRes + ix0,
            iz0*(kRes*kRes) + iy1*kRes + ix1,
            iz1*(kRes*kRes) + iy0*kRes + ix0,
            iz1*(kRes*kRes) + iy0*kRes + ix1,
            iz1*(kRes*kRes) + iy1*kRes + ix0,
            iz1*(kRes*kRes) + iy1*kRes + ix1 };
        const float cw[8] = {
            gz0*gy0*gx0, gz0*gy0*fx, gz0*fy*gx0, gz0*fy*fx,
            fz *gy0*gx0, fz *gy0*fx, fz *fy*gx0, fz *fy*fx };

        #pragma unroll
        for (int cn = 0; cn < 8; ++cn) {
            const uint4* vp = (const uint4*)(vox + (size_t)offs[cn] * kRecBytes);
            const uint4 u0 = vp[0], u1 = vp[1];

            float f[28];
            const unsigned wd[7] = { u0.x, u0.y, u0.z, u0.w, u1.x, u1.y, u1.z };
            #pragma unroll
            for (int i = 0; i < 7; ++i) {
                const f2v lo = __builtin_amdgcn_cvt_pk_f32_fp8((int)wd[i], false);
                const f2v hi = __builtin_amdgcn_cvt_pk_f32_fp8((int)wd[i], true);
                f[4*i+0] = lo.x; f[4*i+1] = lo.y; f[4*i+2] = hi.x; f[4*i+3] = hi.y;
            }
            union { unsigned short u; _Float16 h; } cv;
            cv.u = (unsigned short)(u1.w & 0xffffu);
            const float sv = (float)cv.h;

            float r = 0.f, g = 0.f, b = 0.f;
            #pragma unroll
            for (int j = 0; j < 9; ++j) {
                r = fmaf(shm[j], f[j],      r);
                g = fmaf(shm[j], f[9 + j],  g);
                b = fmaf(shm[j], f[18 + j], b);
            }
            const float wc = cw[cn];
            s.rp0 = fmaf(wc, r, s.rp0);
            s.rp1 = fmaf(wc, g, s.rp1);
            s.rp2 = fmaf(wc, b, s.rp2);
            sig   = fmaf(wc, sv, sig);
        }
        sig = fmaxf(sig, 0.0f);
    }
    s.alpha = 1.0f - expf(-sig * dist);
    s.a     = 1.0f - s.alpha + 1e-10f;
    return s;
}

__device__ __forceinline__ float wave_scan_prod(float a, int lane, float& total)
{
    float prod = a;
    #pragma unroll
    for (int off = 1; off < 64; off <<= 1) {
        const float y = __shfl_up(prod, off, 64);
        if (lane >= off) prod *= y;
    }
    float excl = __shfl_up(prod, 1, 64);
    if (lane == 0) excl = 1.0f;
    total = __shfl(prod, 63, 64);
    return excl;
}

// ---------------------------------------------------------------------------
// Render one 256-sample chunk of one ray per wave; lane handles samples
// base+lane+{0,64,128,192}.  Emits S_R,S_G,S_B,S_L (unit carry) + P.
// ---------------------------------------------------------------------------
__global__ __launch_bounds__(256, 3)
void render_chunks(const float* __restrict__ rays_o,
                   const float* __restrict__ rays_d,
                   const unsigned char* __restrict__ vox,
                   float* __restrict__ partials)           // (4096,2,5)
{
    const int lane  = threadIdx.x & 63;
    const int W     = blockIdx.x * 4 + (threadIdx.x >> 6); // 8192 waves
    const int ray   = W >> 1;
    const int chunk = W & 1;

    const float ox = rays_o[3*ray+0], oy = rays_o[3*ray+1], oz = rays_o[3*ray+2];
    const float dx = rays_d[3*ray+0], dy = rays_d[3*ray+1], dz = rays_d[3*ray+2];

    const float ppx = ( kRadius - ox)/dx, pnx = (-kRadius - ox)/dx;
    const float ppy = ( kRadius - oy)/dy, pny = (-kRadius - oy)/dy;
    const float ppz = ( kRadius - oz)/dz, pnz = (-kRadius - oz)/dz;
    const float start  = fmaxf(fminf(ppx, pnx), fmaxf(fminf(ppy, pny), fminf(ppz, pnz)));
    const float t_exit = fminf(fmaxf(ppx, pnx), fminf(fmaxf(ppy, pny), fmaxf(ppz, pnz)));

    const int base = chunk * 256;

    // whole-wave early exit: chunk starts beyond box exit (one-step margin)
    if (start + (float)base * kStep > t_exit + kStep) {
        if (lane == 0) {
            float* p = partials + (size_t)(ray * kChunks + chunk) * 5;
            p[0] = 0.f; p[1] = 0.f; p[2] = 0.f; p[3] = 0.f; p[4] = 1.f;
        }
        return;
    }

    const float dnorm = sqrtf(dx*dx + dy*dy + dz*dz);
    const float dist  = kStep * dnorm;

    float shm[9];
    shm[0] =  0.28209479177387814f;
    shm[1] = -0.4886025119029199f * dy;
    shm[2] =  0.4886025119029199f * dz;
    shm[3] = -0.4886025119029199f * dx;
    shm[4] =  1.0925484305920792f * dx * dy;
    shm[5] = -1.0925484305920792f * dy * dz;
    shm[6] =  0.31539156525252005f * (2.0f*dz*dz - dx*dx - dy*dy);
    shm[7] = -1.0925484305920792f * dx * dz;
    shm[8] =  0.5462742152960396f * (dx*dx - dy*dy);

    const Sample A = eval_sample(base       + lane, start, ox, oy, oz, dx, dy, dz, dist, shm, vox);
    const Sample B = eval_sample(base +  64 + lane, start, ox, oy, oz, dx, dy, dz, dist, shm, vox);
    const Sample C = eval_sample(base + 128 + lane, start, ox, oy, oz, dx, dy, dz, dist, shm, vox);
    const Sample D = eval_sample(base + 192 + lane, start, ox, oy, oz, dx, dy, dz, dist, shm, vox);

    float P0, P1, P2, P3;
    const float eA = wave_scan_prod(A.a, lane, P0);
    const float eB = wave_scan_prod(B.a, lane, P1);
    const float eC = wave_scan_prod(C.a, lane, P2);
    const float eD = wave_scan_prod(D.a, lane, P3);

    const float wA = A.alpha * eA;
    const float wB = B.alpha * P0 * eB;
    const float wC = C.alpha * P0 * P1 * eC;
    const float wD = D.alpha * P0 * P1 * P2 * eD;

    float sR = 0.f, sG = 0.f, sB = 0.f;
    if (A.inb) {
        sR = wA * (1.0f / (1.0f + expf(-A.rp0)));
        sG = wA * (1.0f / (1.0f + expf(-A.rp1)));
        sB = wA * (1.0f / (1.0f + expf(-A.rp2)));
    }
    if (B.inb) {
        sR = fmaf(wB, 1.0f / (1.0f + expf(-B.rp0)), sR);
        sG = fmaf(wB, 1.0f / (1.0f + expf(-B.rp1)), sG);
        sB = fmaf(wB, 1.0f / (1.0f + expf(-B.rp2)), sB);
    }
    if (C.inb) {
        sR = fmaf(wC, 1.0f / (1.0f + expf(-C.rp0)), sR);
        sG = fmaf(wC, 1.0f / (1.0f + expf(-C.rp1)), sG);
        sB = fmaf(wC, 1.0f / (1.0f + expf(-C.rp2)), sB);
    }
    if (D.inb) {
        sR = fmaf(wD, 1.0f / (1.0f + expf(-D.rp0)), sR);
        sG = fmaf(wD, 1.0f / (1.0f + expf(-D.rp1)), sG);
        sB = fmaf(wD, 1.0f / (1.0f + expf(-D.rp2)), sB);
    }
    float sL = wA + wB + wC + wD;
    const float P = P0 * P1 * P2 * P3;

    #pragma unroll
    for (int off = 32; off > 0; off >>= 1) {
        sR += __shfl_down(sR, off, 64);
        sG += __shfl_down(sG, off, 64);
        sB += __shfl_down(sB, off, 64);
        sL += __shfl_down(sL, off, 64);
    }

    if (lane == 0) {
        float* p = partials + (size_t)(ray * kChunks + chunk) * 5;
        p[0] = sR; p[1] = sG; p[2] = sB; p[3] = sL; p[4] = P;
    }
}

// ---------------------------------------------------------------------------
// Stitch chunk partials: acc += carry * S_c ; carry *= P_c.
// ---------------------------------------------------------------------------
__global__ __launch_bounds__(256)
void combine_chunks(const float* __restrict__ partials, float* __restrict__ out)
{
    const int r = blockIdx.x * 256 + threadIdx.x;          // 16 blocks
    const float* p = partials + (size_t)r * (kChunks * 5);

    float carry = 1.0f, aR = 0.f, aG = 0.f, aB = 0.f, aL = 0.f;
    #pragma unroll
    for (int c = 0; c < kChunks; ++c) {
        aR = fmaf(carry, p[c*5 + 0], aR);
        aG = fmaf(carry, p[c*5 + 1], aG);
        aB = fmaf(carry, p[c*5 + 2], aB);
        aL = fmaf(carry, p[c*5 + 3], aL);
        carry *= p[c*5 + 4];
    }
    const float bg = 1.0f - aL;
    out[3*r + 0] = aR + bg;
    out[3*r + 1] = aG + bg;
    out[3*r + 2] = aB + bg;
}

// ---------------------------------------------------------------------------
// Fallback: direct channel-major render (round-1 style) if ws too small.
// ---------------------------------------------------------------------------
#define TRI8(p) (w000*(p)[o000] + w001*(p)[o001] + w010*(p)[o010] + w011*(p)[o011] \
               + w100*(p)[o100] + w101*(p)[o101] + w110*(p)[o110] + w111*(p)[o111])

__global__ __launch_bounds__(256)
void plenoxel_render_direct(const float* __restrict__ rays_o,
                            const float* __restrict__ rays_d,
                            const float* __restrict__ grid,
                            float* __restrict__ out)
{
    const int lane = threadIdx.x & 63;
    const int ray  = blockIdx.x * 4 + (threadIdx.x >> 6);

    const float ox = rays_o[3*ray+0], oy = rays_o[3*ray+1], oz = rays_o[3*ray+2];
    const float dx = rays_d[3*ray+0], dy = rays_d[3*ray+1], dz = rays_d[3*ray+2];

    const float sx = fminf(( kRadius - ox)/dx, (-kRadius - ox)/dx);
    const float sy = fminf(( kRadius - oy)/dy, (-kRadius - oy)/dy);
    const float sz = fminf(( kRadius - oz)/dz, (-kRadius - oz)/dz);
    const float start = fmaxf(sx, fmaxf(sy, sz));
    const float dnorm = sqrtf(dx*dx + dy*dy + dz*dz);

    float shm[9];
    shm[0] =  0.28209479177387814f;
    shm[1] = -0.4886025119029199f * dy;
    shm[2] =  0.4886025119029199f * dz;
    shm[3] = -0.4886025119029199f * dx;
    shm[4] =  1.0925484305920792f * dx * dy;
    shm[5] = -1.0925484305920792f * dy * dz;
    shm[6] =  0.31539156525252005f * (2.0f*dz*dz - dx*dx - dy*dy);
    shm[7] = -1.0925484305920792f * dx * dz;
    shm[8] =  0.5462742152960396f * (dx*dx - dy*dy);

    float carry = 1.0f;
    float accR = 0.f, accG = 0.f, accB = 0.f, accL = 0.f;

    for (int chunk = 0; chunk < kChunks7; ++chunk) {
        const int k = chunk * 64 + lane;
        float alpha = 0.0f, a = 1.0f;
        float rp0 = 0.f, rp1 = 0.f, rp2 = 0.f;
        bool inb = false;

        if (k < kNI) {
            const float t = start + (float)k * kStep;
            const float dist = kStep * dnorm;
            const float px = ox + t*dx, py = oy + t*dy, pz = oz + t*dz;
            inb = (px > -kRadius) && (px < kRadius) &&
                  (py > -kRadius) && (py < kRadius) &&
                  (pz > -kRadius) && (pz < kRadius);
            float sigma = 0.0f;
            if (inb) {
                const float cx = fminf(fmaxf((px*(1.0f/kRadius) + 1.0f)*0.5f*127.0f, 0.0f), 127.0f);
                const float cy = fminf(fmaxf((py*(1.0f/kRadius) + 1.0f)*0.5f*127.0f, 0.0f), 127.0f);
                const float cz = fminf(fmaxf((pz*(1.0f/kRadius) + 1.0f)*0.5f*127.0f, 0.0f), 127.0f);
                const float fx0 = floorf(cx), fy0 = floorf(cy), fz0 = floorf(cz);
                const float fx = cx - fx0, fy = cy - fy0, fz = cz - fz0;
                const int ix0 = (int)fx0, iy0 = (int)fy0, iz0 = (int)fz0;
                const int ix1 = min(ix0 + 1, 127);
                const int iy1 = min(iy0 + 1, 127);
                const int iz1 = min(iz0 + 1, 127);
                const float gx0 = 1.0f - fx, gy0 = 1.0f - fy, gz0 = 1.0f - fz;
                const float w000 = gz0*gy0*gx0, w001 = gz0*gy0*fx;
                const float w010 = gz0*fy *gx0, w011 = gz0*fy *fx;
                const float w100 = fz *gy0*gx0, w101 = fz *gy0*fx;
                const float w110 = fz *fy *gx0, w111 = fz *fy *fx;
                const int o000 = iz0*(kRes*kRes) + iy0*kRes + ix0;
                const int o001 = iz0*(kRes*kRes) + iy0*kRes + ix1;
                const int o010 = iz0*(kRes*kRes) + iy1*kRes + ix0;
                const int o011 = iz0*(kRes*kRes) + iy1*kRes + ix1;
                const int o100 = iz1*(kRes*kRes) + iy0*kRes + ix0;
                const int o101 = iz1*(kRes*kRes) + iy0*kRes + ix1;
                const int o110 = iz1*(kRes*kRes) + iy1*kRes + ix0;
                const int o111 = iz1*(kRes*kRes) + iy1*kRes + ix1;
                #pragma unroll
                for (int kk = 0; kk < 9; ++kk) {
                    rp0 = fmaf(shm[kk], TRI8(grid + (kk     ) * kChStride), rp0);
                    rp1 = fmaf(shm[kk], TRI8(grid + (kk +  9) * kChStride), rp1);
                    rp2 = fmaf(shm[kk], TRI8(grid + (kk + 18) * kChStride), rp2);
                }
                sigma = fmaxf(TRI8(grid + 27 * kChStride), 0.0f);
            }
            alpha = 1.0f - expf(-sigma * dist);
            a     = 1.0f - alpha + 1e-10f;
        }

        float prod = a;
        #pragma unroll
        for (int off = 1; off < 64; off <<= 1) {
            const float y = __shfl_up(prod, off, 64);
            if (lane >= off) prod *= y;
        }
        float excl = __shfl_up(prod, 1, 64);
        if (lane == 0) excl = 1.0f;
        const float trans = carry * excl;
        const float w = alpha * trans;
        if (inb) {
            accR = fmaf(w, 1.0f / (1.0f + expf(-rp0)), accR);
            accG = fmaf(w, 1.0f / (1.0f + expf(-rp1)), accG);
            accB = fmaf(w, 1.0f / (1.0f + expf(-rp2)), accB);
        }
        accL += w;
        carry *= __shfl(prod, 63, 64);
    }

    #pragma unroll
    for (int off = 32; off > 0; off >>= 1) {
        accR += __shfl_down(accR, off, 64);
        accG += __shfl_down(accG, off, 64);
        accB += __shfl_down(accB, off, 64);
        accL += __shfl_down(accL, off, 64);
    }

    if (lane == 0) {
        const float bg = 1.0f - accL;
        out[3*ray + 0] = accR + bg;
        out[3*ray + 1] = accG + bg;
        out[3*ray + 2] = accB + bg;
    }
}

extern "C" void kernel_launch(void* const* d_in, const int* in_sizes, int n_in,
                              void* d_out, int out_size, void* d_ws, size_t ws_size,
                              hipStream_t stream) {
    const float* rays_o = (const float*)d_in[0];
    const float* rays_d = (const float*)d_in[1];
    const float* data   = (const float*)d_in[2];   // (1,28,128,128,128)
    float* out = (float*)d_out;

    const size_t partBytes = (size_t)kNRays * kChunks * 5 * sizeof(float);
    const size_t need = kVoxBytes + partBytes;     // ~64.2 MB

    if (ws_size >= need) {
        unsigned char* vox = (unsigned char*)d_ws;
        float* partials = (float*)((char*)d_ws + kVoxBytes);

        hipLaunchKernelGGL(convert_grid,
                           dim3(kChStride / 256), dim3(256), 0, stream,
                           data, vox);
        hipLaunchKernelGGL(render_chunks,
                           dim3(kNRays * kChunks / 4), dim3(256), 0, stream,
                           rays_o, rays_d, vox, partials);
        hipLaunchKernelGGL(combine_chunks,
                           dim3(kNRays / 256), dim3(256), 0, stream,
                           partials, out);
    } else {
        hipLaunchKernelGGL(plenoxel_render_direct,
                           dim3(kNRays / 4), dim3(256), 0, stream,
                           rays_o, rays_d, data, out);
    }
}